// Round 1
// baseline (27102.679 us; speedup 1.0000x reference)
//
#include <hip/hip_runtime.h>
#include <hip/hip_cooperative_groups.h>

namespace cg = cooperative_groups;

#define NB 256      // batch
#define NT 512      // time steps
#define NH 1024     // hidden
#define BH (NB * NH)
#define GRID_WGS 256
#define BLOCK_THREADS 512
#define GSTRIDE (GRID_WGS * BLOCK_THREADS)

typedef __attribute__((ext_vector_type(8))) __bf16 bfrag;
typedef __attribute__((ext_vector_type(4))) float f32x4;
typedef __attribute__((ext_vector_type(8))) unsigned short u16x8;

// static device scratch (avoids any dependence on ws_size)
__device__ unsigned short g_W1[NH * NH];    // W_hh1 bf16 [j][k]
__device__ unsigned short g_W2i[NH * NH];   // W_ih2 bf16 [j][k]
__device__ unsigned short g_W2h[NH * NH];   // W_hh2 bf16 [j][k]
__device__ unsigned short g_h1[2 * BH];     // h1 double buffer, h1(t) in buf[t&1]
__device__ unsigned short g_h2[2 * BH];     // h2 double buffer, h2(t) in buf[t&1]

__device__ __forceinline__ unsigned short f2bf(float f) {
  union { float f; unsigned u; } v; v.f = f;
  unsigned r = v.u + 0x7FFFu + ((v.u >> 16) & 1u);  // round-to-nearest-even
  return (unsigned short)(r >> 16);
}
__device__ __forceinline__ float bf2f(unsigned short u) {
  union { unsigned u; float f; } v; v.u = ((unsigned)u) << 16;
  return v.f;
}

// out(t)[r,c] = dot(h2(t)[r,:], Wlin[c,:]) + blin[c]; bid<64, waves 0..3, 1 row/wave
__device__ __forceinline__ void out_dot(const unsigned short* __restrict__ h2,
                                        const float* __restrict__ Wlin,
                                        const float* __restrict__ blin,
                                        float* __restrict__ out,
                                        int bid, int wid, int lane, int t) {
  const int r_g = (bid >> 3) * 32 + (bid & 7) * 4 + wid;  // 0..255
  const int c = lane >> 5;                                 // 0/1 per half-wave
  const int l32 = lane & 31;
  const unsigned short* hp = h2 + r_g * NH + l32 * 32;
  const float* wl = Wlin + c * NH + l32 * 32;
  float s = 0.f;
#pragma unroll
  for (int j = 0; j < 32; j += 8) {
    u16x8 hv = *reinterpret_cast<const u16x8*>(hp + j);
#pragma unroll
    for (int e = 0; e < 8; ++e) s = fmaf(bf2f(hv[e]), wl[j + e], s);
  }
#pragma unroll
  for (int m = 1; m < 32; m <<= 1) s += __shfl_xor(s, m);
  if (l32 == 0) out[r_g * (2 * NT) + c * NT + t] = s + blin[c];
}

__global__ void __launch_bounds__(BLOCK_THREADS, 2) rnn_kernel(
    const float* __restrict__ x,     // [B][2][T]
    const float* __restrict__ Wi1,   // [H][2]
    const float* __restrict__ Whh1,  // [H][H]
    const float* __restrict__ Wih2,  // [H][H]
    const float* __restrict__ Whh2,  // [H][H]
    const float* __restrict__ bih1,
    const float* __restrict__ bhh1,
    const float* __restrict__ bih2,
    const float* __restrict__ bhh2,
    const float* __restrict__ Wlin,  // [2][H]
    const float* __restrict__ blin,  // [2]
    float* __restrict__ out)         // [B][2][T]
{
  cg::grid_group grid = cg::this_grid();
  const int bid = blockIdx.x;
  const int tid = threadIdx.x;

  // ---- preamble: fp32->bf16 weights, zero parity-1 h buffers (the "t=-1" state)
  {
    const int gtid = bid * BLOCK_THREADS + tid;
    for (int i = gtid; i < NH * NH; i += GSTRIDE) {
      g_W1[i]  = f2bf(Whh1[i]);
      g_W2i[i] = f2bf(Wih2[i]);
      g_W2h[i] = f2bf(Whh2[i]);
    }
    for (int i = gtid; i < BH; i += GSTRIDE) {
      g_h1[BH + i] = 0;
      g_h2[BH + i] = 0;
    }
  }
  grid.sync();

  // tile decomposition: WG (mb,nb) owns output rows [mb*32,+32), cols [nb*32,+32)
  const int mb = bid >> 5, nb = bid & 31;
  const int wid = tid >> 6, lane = tid & 63;
  const int kh = wid >> 2;                 // 2-way K split
  const int qr = (wid >> 1) & 1, qc = wid & 1;  // 16x16 quadrant
  const int fr = lane & 15;
  const int kb = kh * 512 + ((lane >> 4) << 3); // k base for this lane
  const int rowA = mb * 32 + qr * 16 + fr;      // A-frag row (batch index)
  const int colB = nb * 32 + qc * 16 + fr;      // B-frag col (hidden index)

  __shared__ float redA[2][32][32];
  __shared__ float redB[2][32][32];

  // phase p: A(p)=h1(p) [p<NT] || B(p-1)=h2(p-1) [p>=1] || out(p-2) [p>=2]
  for (int p = 0; p <= NT; ++p) {
    const unsigned short* h1_prev = g_h1 + ((p + 1) & 1) * BH; // h1(p-1)
    const unsigned short* h2_pp   = g_h2 + (p & 1) * BH;       // h2(p-2)
    unsigned short* h1_cur = g_h1 + (p & 1) * BH;              // h1(p) dest
    unsigned short* h2_cur = g_h2 + ((p + 1) & 1) * BH;        // h2(p-1) dest

    f32x4 accA = {0.f, 0.f, 0.f, 0.f};
    f32x4 accB = {0.f, 0.f, 0.f, 0.f};

    if (p < NT) {  // h1(p) = tanh(h1(p-1)@W1^T + x-term + b1)
      const unsigned short* pA = h1_prev + rowA * NH + kb;
      const unsigned short* pW = g_W1 + colB * NH + kb;
#pragma unroll
      for (int k0 = 0; k0 < 512; k0 += 32)
        accA = __builtin_amdgcn_mfma_f32_16x16x32_bf16(
            *reinterpret_cast<const bfrag*>(pA + k0),
            *reinterpret_cast<const bfrag*>(pW + k0), accA, 0, 0, 0);
    }
    if (p >= 1) {  // h2(p-1) = tanh(h1(p-1)@W2i^T + h2(p-2)@W2h^T + b2)
      const unsigned short* pA1 = h1_prev + rowA * NH + kb;
      const unsigned short* pW1 = g_W2i + colB * NH + kb;
#pragma unroll
      for (int k0 = 0; k0 < 512; k0 += 32)
        accB = __builtin_amdgcn_mfma_f32_16x16x32_bf16(
            *reinterpret_cast<const bfrag*>(pA1 + k0),
            *reinterpret_cast<const bfrag*>(pW1 + k0), accB, 0, 0, 0);
      const unsigned short* pA2 = h2_pp + rowA * NH + kb;
      const unsigned short* pW2 = g_W2h + colB * NH + kb;
#pragma unroll
      for (int k0 = 0; k0 < 512; k0 += 32)
        accB = __builtin_amdgcn_mfma_f32_16x16x32_bf16(
            *reinterpret_cast<const bfrag*>(pA2 + k0),
            *reinterpret_cast<const bfrag*>(pW2 + k0), accB, 0, 0, 0);
    }

    {  // C/D layout: col = lane&15, row = (lane>>4)*4 + r   [guide §3, m89]
      const int rr = qr * 16 + ((lane >> 4) << 2);
      const int cc = qc * 16 + (lane & 15);
#pragma unroll
      for (int r = 0; r < 4; ++r) {
        redA[kh][rr + r][cc] = accA[r];
        redB[kh][rr + r][cc] = accB[r];
      }
    }
    __syncthreads();

    if (p < NT) {
#pragma unroll
      for (int e = 0; e < 2; ++e) {
        const int idx = tid * 2 + e;
        const int rl = idx >> 5, cl = idx & 31;
        const int grow = mb * 32 + rl, gcol = nb * 32 + cl;
        float v = redA[0][rl][cl] + redA[1][rl][cl] + bih1[gcol] + bhh1[gcol]
                + x[grow * (2 * NT) + p] * Wi1[gcol * 2]
                + x[grow * (2 * NT) + NT + p] * Wi1[gcol * 2 + 1];
        h1_cur[grow * NH + gcol] = f2bf(tanhf(v));
      }
    }
    if (p >= 1) {
#pragma unroll
      for (int e = 0; e < 2; ++e) {
        const int idx = tid * 2 + e;
        const int rl = idx >> 5, cl = idx & 31;
        const int grow = mb * 32 + rl, gcol = nb * 32 + cl;
        float v = redB[0][rl][cl] + redB[1][rl][cl] + bih2[gcol] + bhh2[gcol];
        h2_cur[grow * NH + gcol] = f2bf(tanhf(v));
      }
    }
    if (p >= 2 && bid < 64 && wid < 4)
      out_dot(h2_pp, Wlin, blin, out, bid, wid, lane, p - 2);

    grid.sync();
  }

  // final output t = NT-1: h2(NT-1) lives in buf[(NT-1)&1] = buf[1]
  if (bid < 64 && wid < 4)
    out_dot(g_h2 + ((NT + 1) & 1) * BH, Wlin, blin, out, bid, wid, lane, NT - 1);
}

extern "C" void kernel_launch(void* const* d_in, const int* in_sizes, int n_in,
                              void* d_out, int out_size, void* d_ws, size_t ws_size,
                              hipStream_t stream) {
  (void)in_sizes; (void)n_in; (void)d_ws; (void)ws_size; (void)out_size;
  const float* x    = (const float*)d_in[0];
  const float* Wi1  = (const float*)d_in[1];
  const float* Whh1 = (const float*)d_in[2];
  const float* bih1 = (const float*)d_in[3];
  const float* bhh1 = (const float*)d_in[4];
  const float* Wih2 = (const float*)d_in[5];
  const float* Whh2 = (const float*)d_in[6];
  const float* bih2 = (const float*)d_in[7];
  const float* bhh2 = (const float*)d_in[8];
  const float* Wlin = (const float*)d_in[9];
  const float* blin = (const float*)d_in[10];
  // d_in[11] = future (0 in this benchmark)
  float* out = (float*)d_out;

  void* args[] = { (void*)&x, (void*)&Wi1, (void*)&Whh1, (void*)&Wih2, (void*)&Whh2,
                   (void*)&bih1, (void*)&bhh1, (void*)&bih2, (void*)&bhh2,
                   (void*)&Wlin, (void*)&blin, (void*)&out };
  hipLaunchCooperativeKernel((void*)rnn_kernel, dim3(GRID_WGS), dim3(BLOCK_THREADS),
                             args, 0, stream);
}

// Round 2
// 22360.081 us; speedup vs baseline: 1.2121x; 1.2121x over previous
//
#include <hip/hip_runtime.h>
#include <hip/hip_cooperative_groups.h>

namespace cg = cooperative_groups;

#define NB 256      // batch
#define NT 512      // time steps
#define NH 1024     // hidden
#define BH (NB * NH)
#define GRID_WGS 256
#define BLOCK_THREADS 512
#define GSTRIDE (GRID_WGS * BLOCK_THREADS)

typedef __attribute__((ext_vector_type(8))) __bf16 bfrag;
typedef __attribute__((ext_vector_type(4))) float f32x4;
typedef __attribute__((ext_vector_type(8))) unsigned short u16x8;

// h-state double buffers: h(t) lives in buf[t&1]
__device__ unsigned short g_h1[2 * BH];
__device__ unsigned short g_h2[2 * BH];

__device__ __forceinline__ unsigned short f2bf(float f) {
  union { float f; unsigned u; } v; v.f = f;
  unsigned r = v.u + 0x7FFFu + ((v.u >> 16) & 1u);  // RTE
  return (unsigned short)(r >> 16);
}
__device__ __forceinline__ float bf2f(unsigned short u) {
  union { unsigned u; float f; } v; v.u = ((unsigned)u) << 16;
  return v.f;
}

// convert 8 consecutive fp32 -> bf16 fragment
__device__ __forceinline__ bfrag cvt8(const float* __restrict__ p) {
  f32x4 a = *reinterpret_cast<const f32x4*>(p);
  f32x4 b = *reinterpret_cast<const f32x4*>(p + 4);
  u16x8 u;
#pragma unroll
  for (int i = 0; i < 4; ++i) { u[i] = f2bf(a[i]); u[i + 4] = f2bf(b[i]); }
  union { u16x8 u; bfrag b; } c; c.u = u; return c.b;
}

// out(t)[r,c] = dot(h2(t)[r,:], Wlin[c,:]) + blin[c]; bid<64, waves 0..3, 1 row/wave
__device__ __forceinline__ void out_dot(const unsigned short* __restrict__ h2,
                                        const float* __restrict__ Wlin,
                                        const float* __restrict__ blin,
                                        float* __restrict__ out,
                                        int bid, int wid, int lane, int t) {
  const int r_g = (bid >> 3) * 32 + (bid & 7) * 4 + wid;  // 0..255
  const int c = lane >> 5;
  const int l32 = lane & 31;
  const unsigned short* hp = h2 + r_g * NH + l32 * 32;
  const float* wl = Wlin + c * NH + l32 * 32;
  float s = 0.f;
#pragma unroll
  for (int j = 0; j < 32; j += 8) {
    u16x8 hv = *reinterpret_cast<const u16x8*>(hp + j);
#pragma unroll
    for (int e = 0; e < 8; ++e) s = fmaf(bf2f(hv[e]), wl[j + e], s);
  }
#pragma unroll
  for (int m = 1; m < 32; m <<= 1) s += __shfl_xor(s, m);
  if (l32 == 0) out[r_g * (2 * NT) + c * NT + t] = s + blin[c];
}

__global__ void __launch_bounds__(BLOCK_THREADS, 2) rnn_kernel(
    const float* __restrict__ x,     // [B][2][T]
    const float* __restrict__ Wi1,   // [H][2]
    const float* __restrict__ Whh1,  // [H][H]
    const float* __restrict__ Wih2,  // [H][H]
    const float* __restrict__ Whh2,  // [H][H]
    const float* __restrict__ bih1,
    const float* __restrict__ bhh1,
    const float* __restrict__ bih2,
    const float* __restrict__ bhh2,
    const float* __restrict__ Wlin,  // [2][H]
    const float* __restrict__ blin,  // [2]
    float* __restrict__ out)         // [B][2][T]
{
  cg::grid_group grid = cg::this_grid();
  const int bid = blockIdx.x;
  const int tid = threadIdx.x;
  const int w = tid >> 6, lane = tid & 63;
  const int mb = bid >> 6, nb = bid & 63;   // 4 row-tiles x 64 col-tiles

  // zero the parity-1 buffers (the t = -1 state)
  {
    const int gtid = bid * BLOCK_THREADS + tid;
    for (int i = gtid; i < BH; i += GSTRIDE) {
      g_h1[BH + i] = 0;
      g_h2[BH + i] = 0;
    }
  }

  // ---- persistent weight fragments: this wave's K-slice [w*128, w*128+128)
  // B-frag mapping (verified R1): col = lane&15, k = (lane>>4)*8 + j
  const int fr = lane & 15;
  const int ko = (lane >> 4) << 3;        // 0,8,16,24
  const int kbase = w * 128;
  const int colW = nb * 16 + fr;
  bfrag w1[4], w2i[4], w2h[4];
#pragma unroll
  for (int st = 0; st < 4; ++st) {
    const int off = colW * NH + kbase + st * 32 + ko;
    w1[st]  = cvt8(Whh1 + off);
    w2i[st] = cvt8(Wih2 + off);
    w2h[st] = cvt8(Whh2 + off);
  }

  // ---- per-thread epilogue constants (2 adjacent cols of one row)
  const int idx = tid * 2;
  const int rl = idx >> 4, cl = idx & 15;          // local row 0..63, col (even)
  const int grow = mb * 64 + rl, gcol = nb * 16 + cl;
  const float b1s0 = bih1[gcol] + bhh1[gcol];
  const float b1s1 = bih1[gcol + 1] + bhh1[gcol + 1];
  const float b2s0 = bih2[gcol] + bhh2[gcol];
  const float b2s1 = bih2[gcol + 1] + bhh2[gcol + 1];
  const float wi00 = Wi1[gcol * 2],       wi01 = Wi1[gcol * 2 + 1];
  const float wi10 = Wi1[(gcol + 1) * 2], wi11 = Wi1[(gcol + 1) * 2 + 1];
  const float* xrow = x + grow * (2 * NT);
  unsigned short* const h1w = (unsigned short*)0;  // (placeholder, unused)
  (void)h1w;

  __shared__ float redA[8][64][18];   // pad 18 -> <=2-way bank aliasing on writes
  __shared__ float redB[8][64][18];

  const int arow0 = mb * 64 + fr;     // A-frag row base (+ mf*16)
  const int prow = (lane >> 4) << 2;  // C/D row base within 16x16 frag

  grid.sync();

  // phase p: A(p)=h1(p) [p<NT] || B(p-1)=h2(p-1) [p>=1] || out(p-2) [p>=2]
  for (int p = 0; p <= NT; ++p) {
    const unsigned short* h1_prev = g_h1 + ((p + 1) & 1) * BH; // h1(p-1)
    const unsigned short* h2_pp   = g_h2 + (p & 1) * BH;       // h2(p-2)
    unsigned short* h1_cur = g_h1 + (p & 1) * BH;              // h1(p)
    unsigned short* h2_cur = g_h2 + ((p + 1) & 1) * BH;        // h2(p-1)

    f32x4 accA[4] = {}; f32x4 accB[4] = {};

#pragma unroll
    for (int mf = 0; mf < 4; ++mf) {
      const unsigned short* pa1 = h1_prev + (arow0 + mf * 16) * NH + kbase + ko;
      const unsigned short* pa2 = h2_pp   + (arow0 + mf * 16) * NH + kbase + ko;
#pragma unroll
      for (int st = 0; st < 4; ++st) {
        bfrag a1 = *reinterpret_cast<const bfrag*>(pa1 + st * 32);
        if (p < NT)
          accA[mf] = __builtin_amdgcn_mfma_f32_16x16x32_bf16(a1, w1[st], accA[mf], 0, 0, 0);
        if (p >= 1) {
          accB[mf] = __builtin_amdgcn_mfma_f32_16x16x32_bf16(a1, w2i[st], accB[mf], 0, 0, 0);
          bfrag a2 = *reinterpret_cast<const bfrag*>(pa2 + st * 32);
          accB[mf] = __builtin_amdgcn_mfma_f32_16x16x32_bf16(a2, w2h[st], accB[mf], 0, 0, 0);
        }
      }
    }

    // write k-partials to LDS  (C/D: col = lane&15, row = (lane>>4)*4 + r)
#pragma unroll
    for (int mf = 0; mf < 4; ++mf) {
#pragma unroll
      for (int r = 0; r < 4; ++r) {
        redA[w][mf * 16 + prow + r][fr] = accA[mf][r];
        redB[w][mf * 16 + prow + r][fr] = accB[mf][r];
      }
    }
    __syncthreads();

    // 8-way k-reduction + fused epilogue (2 adjacent cols per thread)
    float sA0 = 0.f, sA1 = 0.f, sB0 = 0.f, sB1 = 0.f;
#pragma unroll
    for (int u = 0; u < 8; ++u) {
      sA0 += redA[u][rl][cl];  sA1 += redA[u][rl][cl + 1];
      sB0 += redB[u][rl][cl];  sB1 += redB[u][rl][cl + 1];
    }
    if (p < NT) {
      const float x0 = xrow[p], x1 = xrow[NT + p];
      const float v0 = sA0 + b1s0 + x0 * wi00 + x1 * wi01;
      const float v1 = sA1 + b1s1 + x0 * wi10 + x1 * wi11;
      const unsigned pack = (unsigned)f2bf(tanhf(v0)) | ((unsigned)f2bf(tanhf(v1)) << 16);
      *reinterpret_cast<unsigned*>(h1_cur + grow * NH + gcol) = pack;
    }
    if (p >= 1) {
      const float v0 = sB0 + b2s0;
      const float v1 = sB1 + b2s1;
      const unsigned pack = (unsigned)f2bf(tanhf(v0)) | ((unsigned)f2bf(tanhf(v1)) << 16);
      *reinterpret_cast<unsigned*>(h2_cur + grow * NH + gcol) = pack;
    }
    if (p >= 2 && bid < 64 && w < 4)
      out_dot(h2_pp, Wlin, blin, out, bid, w, lane, p - 2);

    grid.sync();
  }

  // final output t = NT-1: h2(NT-1) lives in buf[1]
  if (bid < 64 && w < 4)
    out_dot(g_h2 + BH, Wlin, blin, out, bid, w, lane, NT - 1);
}

extern "C" void kernel_launch(void* const* d_in, const int* in_sizes, int n_in,
                              void* d_out, int out_size, void* d_ws, size_t ws_size,
                              hipStream_t stream) {
  (void)in_sizes; (void)n_in; (void)d_ws; (void)ws_size; (void)out_size;
  const float* x    = (const float*)d_in[0];
  const float* Wi1  = (const float*)d_in[1];
  const float* Whh1 = (const float*)d_in[2];
  const float* bih1 = (const float*)d_in[3];
  const float* bhh1 = (const float*)d_in[4];
  const float* Wih2 = (const float*)d_in[5];
  const float* Whh2 = (const float*)d_in[6];
  const float* bih2 = (const float*)d_in[7];
  const float* bhh2 = (const float*)d_in[8];
  const float* Wlin = (const float*)d_in[9];
  const float* blin = (const float*)d_in[10];
  float* out = (float*)d_out;

  void* args[] = { (void*)&x, (void*)&Wi1, (void*)&Whh1, (void*)&Wih2, (void*)&Whh2,
                   (void*)&bih1, (void*)&bhh1, (void*)&bih2, (void*)&bhh2,
                   (void*)&Wlin, (void*)&blin, (void*)&out };
  hipLaunchCooperativeKernel((void*)rnn_kernel, dim3(GRID_WGS), dim3(BLOCK_THREADS),
                             args, 0, stream);
}